// Round 9
// baseline (140.751 us; speedup 1.0000x reference)
//
#include <hip/hip_runtime.h>

#define NNODES 4096
#define DIM 512
#define QKVD 1536
#define MAXE 96   // bucket capacity per dst row
#define STAGE 56  // LDS-staged entries per row (P(deg>=56 | Poisson(32)) ~ 1e-5)

typedef __bf16 bf16_t;
typedef bf16_t bf16x8 __attribute__((ext_vector_type(8)));
typedef bf16_t bf16x2 __attribute__((ext_vector_type(2)));
typedef float f32x4 __attribute__((ext_vector_type(4)));
typedef unsigned int uint;

#define GLOAD_LDS16(gp, lp)                                                        \
  __builtin_amdgcn_global_load_lds((const __attribute__((address_space(1))) void*)(gp), \
                                   (__attribute__((address_space(3))) void*)(lp), 16, 0, 0)

// ---------------- fused casts f32 -> bf16 (+ deg zero) ----------------
__global__ __launch_bounds__(256) void cast_all_k(const float* __restrict__ x,
                                                  const float* __restrict__ wqkv,
                                                  const float* __restrict__ wo,
                                                  const float* __restrict__ w1,
                                                  bf16_t* __restrict__ xb,
                                                  bf16_t* __restrict__ wqkvb,
                                                  bf16_t* __restrict__ wob,
                                                  bf16_t* __restrict__ w1b,
                                                  uint* __restrict__ deg) {
  int i = blockIdx.x * 256 + threadIdx.x;
  if (blockIdx.x < 16) deg[i] = 0u;  // 16*256 = 4096 rows
  const float* src;
  bf16_t* dst;
  int off;
  if (i < 524288) { src = x; dst = xb; off = i; }
  else if (i < 720896) { src = wqkv; dst = wqkvb; off = i - 524288; }
  else if (i < 786432) { src = wo; dst = wob; off = i - 720896; }
  else { src = w1; dst = w1b; off = i - 786432; }
  float4 v = ((const float4*)src)[off];
  dst[4 * off + 0] = (bf16_t)v.x;
  dst[4 * off + 1] = (bf16_t)v.y;
  dst[4 * off + 2] = (bf16_t)v.z;
  dst[4 * off + 3] = (bf16_t)v.w;
}

// ---------------- bucket CSR fill ----------------
__global__ __launch_bounds__(256) void fill_bucket_k(const int* __restrict__ ei,
                                                     uint* __restrict__ deg,
                                                     int* __restrict__ colv,
                                                     uint* __restrict__ eidv, int E) {
  int e = blockIdx.x * 256 + threadIdx.x;
  if (e < E) {
    int src = ei[e] & (NNODES - 1);
    int dst = ei[E + e] & (NNODES - 1);
    uint pos = atomicAdd(&deg[dst], 1u);
    if (pos < MAXE) {
      colv[dst * MAXE + pos] = src;
      eidv[dst * MAXE + pos] = (uint)e + 1u;  // 0 reserved for diagonal self-entry
    }
  }
}

// ---------------- bf16 MFMA GEMM 128x128 (QKV), C = A @ B^T + bias, bf16 out ----------------
__global__ __launch_bounds__(256) void gemm128_bt(const bf16_t* __restrict__ A,
                                                  const bf16_t* __restrict__ B,
                                                  const float* __restrict__ bias,
                                                  bf16_t* __restrict__ Cout,
                                                  int M, int Nt, int K) {
  __shared__ bf16_t As[128][40];
  __shared__ bf16_t Bs[128][40];
  const int t = threadIdx.x;
  const int lane = t & 63, w = t >> 6;
  const int wr = (w >> 1) * 64, wc = (w & 1) * 64;
  const int m0 = blockIdx.y * 128, n0 = blockIdx.x * 128;
  f32x4 acc[4][4] = {};
  const int r_ld = t >> 2;
  const int c_ld = (t & 3) * 8;

  for (int k0 = 0; k0 < K; k0 += 32) {
#pragma unroll
    for (int seg = 0; seg < 2; ++seg) {
      int row = r_ld + seg * 64;
      *(int4*)&As[row][c_ld] = *(const int4*)(A + (long)(m0 + row) * K + k0 + c_ld);
      *(int4*)&Bs[row][c_ld] = *(const int4*)(B + (long)(n0 + row) * K + k0 + c_ld);
    }
    __syncthreads();
    bf16x8 af[4], bfr[4];
    const int kg = (lane >> 4) * 8;
#pragma unroll
    for (int i = 0; i < 4; ++i) {
      af[i] = *(const bf16x8*)&As[wr + i * 16 + (lane & 15)][kg];
      bfr[i] = *(const bf16x8*)&Bs[wc + i * 16 + (lane & 15)][kg];
    }
#pragma unroll
    for (int i = 0; i < 4; ++i)
#pragma unroll
      for (int j = 0; j < 4; ++j)
        acc[i][j] = __builtin_amdgcn_mfma_f32_16x16x32_bf16(af[i], bfr[j], acc[i][j], 0, 0, 0);
    __syncthreads();
  }

  const int cr = (lane >> 4) * 4;
  const int cc = lane & 15;
#pragma unroll
  for (int i = 0; i < 4; ++i) {
#pragma unroll
    for (int j = 0; j < 4; ++j) {
      int n = n0 + wc + j * 16 + cc;
      float bv = bias[n];
#pragma unroll
      for (int r = 0; r < 4; ++r) {
        int m = m0 + wr + i * 16 + cr + r;
        Cout[(long)m * Nt + n] = (bf16_t)(acc[i][j][r] + bv);
      }
    }
  }
}

// ---------------- bf16 MFMA GEMM: C = A @ B^T + bias, tile 128x64 (Wo/FFN) ----------------
template <bool OUT_BF16>
__global__ __launch_bounds__(256) void gemm_bt(const bf16_t* __restrict__ A,
                                               const bf16_t* __restrict__ B,
                                               const float* __restrict__ bias,
                                               void* __restrict__ Cout,
                                               int M, int Nt, int K) {
  __shared__ bf16_t As[128][40];
  __shared__ bf16_t Bs[64][40];
  const int t = threadIdx.x;
  const int lane = t & 63, w = t >> 6;
  const int wr = (w >> 1) * 64, wc = (w & 1) * 32;
  const int m0 = blockIdx.y * 128, n0 = blockIdx.x * 64;
  f32x4 acc[4][2] = {};
  const int r_ld = t >> 2;
  const int c_ld = (t & 3) * 8;

  for (int k0 = 0; k0 < K; k0 += 32) {
    *(int4*)&As[r_ld][c_ld] = *(const int4*)(A + (long)(m0 + r_ld) * K + k0 + c_ld);
    *(int4*)&As[r_ld + 64][c_ld] = *(const int4*)(A + (long)(m0 + r_ld + 64) * K + k0 + c_ld);
    *(int4*)&Bs[r_ld][c_ld] = *(const int4*)(B + (long)(n0 + r_ld) * K + k0 + c_ld);
    __syncthreads();
    bf16x8 af[4], bfr[2];
    const int kg = (lane >> 4) * 8;
#pragma unroll
    for (int i = 0; i < 4; ++i)
      af[i] = *(const bf16x8*)&As[wr + i * 16 + (lane & 15)][kg];
#pragma unroll
    for (int j = 0; j < 2; ++j)
      bfr[j] = *(const bf16x8*)&Bs[wc + j * 16 + (lane & 15)][kg];
#pragma unroll
    for (int i = 0; i < 4; ++i)
#pragma unroll
      for (int j = 0; j < 2; ++j)
        acc[i][j] = __builtin_amdgcn_mfma_f32_16x16x32_bf16(af[i], bfr[j], acc[i][j], 0, 0, 0);
    __syncthreads();
  }

  const int cr = (lane >> 4) * 4;
  const int cc = lane & 15;
#pragma unroll
  for (int i = 0; i < 4; ++i) {
#pragma unroll
    for (int j = 0; j < 2; ++j) {
      int n = n0 + wc + j * 16 + cc;
      float bv = bias[n];
#pragma unroll
      for (int r = 0; r < 4; ++r) {
        int m = m0 + wr + i * 16 + cr + r;
        float vv = acc[i][j][r] + bv;
        if (OUT_BF16)
          ((bf16_t*)Cout)[(long)m * Nt + n] = (bf16_t)vv;
        else
          ((float*)Cout)[(long)m * Nt + n] = vv;
      }
    }
  }
}

// ---------------- fused sparse attention with LDS bulk staging ----------------
// one block (512 thr, 8 waves) per dst row. K rows async-staged to LDS (zero VGPR),
// scores from LDS; same buffer reused for V (staged during softmax). Tail (deg>=STAGE)
// falls back to inline global gathers.
__global__ __launch_bounds__(512) void attn_stage_k(const bf16_t* __restrict__ qkv,
                                                    const float* __restrict__ ew,
                                                    const uint* __restrict__ deg,
                                                    const int* __restrict__ colv,
                                                    const uint* __restrict__ eidv,
                                                    bf16_t* __restrict__ outb) {
  __shared__ __align__(16) bf16_t kvs[STAGE][DIM];  // 56 KB staging (K, then V, then vacc alias)
  __shared__ float scs[8][MAXE + 1];
  __shared__ int srcs[MAXE + 1];
  __shared__ uint eids[MAXE + 1];
  __shared__ int vld[MAXE + 1];
  __shared__ float invs_s[8];

  const int i = blockIdx.x;
  const int t = threadIdx.x;
  const int lane = t & 63, w = t >> 6;  // w in 0..7

  uint dg = deg[i];
  int L = (dg < (uint)MAXE) ? (int)dg : MAXE;
  int n = L + 1;
  int ns = (n < STAGE) ? n : STAGE;  // staged entries

  if (t < L) {
    srcs[t] = colv[i * MAXE + t];
    eids[t] = eidv[i * MAXE + t];
  }
  if (t == L) { srcs[L] = i; eids[L] = 0u; }
  __syncthreads();

  // ---- issue K staging: wave w -> rows w, w+8, ... (async, zero VGPR) ----
  for (int e = w; e < ns; e += 8)
    GLOAD_LDS16(qkv + (long)srcs[e] * QKVD + DIM + lane * 8, &kvs[e][0]);

  // Q row (overlaps staging)
  const bf16x8 qv = *(const bf16x8*)(qkv + (long)i * QKVD + lane * 8);

  // ---- dedupe (last edge-id wins per src) overlaps K staging ----
  if (t < n) {
    int sj = srcs[t];
    uint my = eids[t];
    int ok = 1;
    for (int j = 0; j < n; ++j)
      ok &= !((srcs[j] == sj) & (eids[j] > my));
    vld[t] = ok;
  }
  __syncthreads();  // drains K loads (vmcnt 0 before barrier)

  // ---- scores from LDS K ----
  for (int e = w; e < ns; e += 8) {
    const bf16x8 kr = *(const bf16x8*)&kvs[e][lane * 8];
    float d = 0.f;
#pragma unroll
    for (int j = 0; j < 8; ++j) d += (float)qv[j] * (float)kr[j];
#pragma unroll
    for (int o = 1; o < 8; o <<= 1) d += __shfl_xor(d, o);
    if ((lane & 7) == 0) {
      uint id = eids[e];
      float b = (id == 0u) ? 0.f : ew[id - 1u];
      scs[lane >> 3][e] = vld[e] ? (d * 0.125f + b) : -1e30f;
    }
  }
  // tail entries from global
  for (int e = STAGE + w; e < n; e += 8) {
    const bf16x8 ka = *(const bf16x8*)(qkv + (long)srcs[e] * QKVD + DIM + lane * 8);
    float d = 0.f;
#pragma unroll
    for (int j = 0; j < 8; ++j) d += (float)qv[j] * (float)ka[j];
#pragma unroll
    for (int o = 1; o < 8; o <<= 1) d += __shfl_xor(d, o);
    if ((lane & 7) == 0) {
      uint id = eids[e];
      float b = (id == 0u) ? 0.f : ew[id - 1u];
      scs[lane >> 3][e] = vld[e] ? (d * 0.125f + b) : -1e30f;
    }
  }
  __syncthreads();  // all K reads done -> kvs reusable

  // ---- issue V staging into the same buffer; loads fly during softmax ----
  for (int e = w; e < ns; e += 8)
    GLOAD_LDS16(qkv + (long)srcs[e] * QKVD + 2 * DIM + lane * 8, &kvs[e][0]);

  // ---- softmax: wave w handles head w (touches scs only) ----
  {
    float m = -1e30f;
    for (int e = lane; e < n; e += 64) m = fmaxf(m, scs[w][e]);
#pragma unroll
    for (int o = 32; o > 0; o >>= 1) m = fmaxf(m, __shfl_xor(m, o));
    float ps = 0.f;
    for (int e = lane; e < n; e += 64) {
      float ev = __expf(scs[w][e] - m);
      scs[w][e] = ev;  // invalid entries become exactly 0
      ps += ev;
    }
#pragma unroll
    for (int o = 32; o > 0; o >>= 1) ps += __shfl_xor(ps, o);
    if (lane == 0) invs_s[w] = 1.f / ps;
  }
  __syncthreads();  // drains V loads; scs/invs ready

  // ---- PV from LDS V ----
  const int hl = lane >> 3;
  float a8[8] = {0.f, 0.f, 0.f, 0.f, 0.f, 0.f, 0.f, 0.f};
  for (int e = w; e < ns; e += 8) {
    const bf16x8 vr = *(const bf16x8*)&kvs[e][lane * 8];
    float p = scs[hl][e];
#pragma unroll
    for (int j = 0; j < 8; ++j) a8[j] += p * (float)vr[j];
  }
  for (int e = STAGE + w; e < n; e += 8) {
    const bf16x8 vv = *(const bf16x8*)(qkv + (long)srcs[e] * QKVD + 2 * DIM + lane * 8);
    float p = scs[hl][e];
#pragma unroll
    for (int j = 0; j < 8; ++j) a8[j] += p * (float)vv[j];
  }
  __syncthreads();  // all V reads done -> kvs reusable as vacc

  // ---- cross-wave reduce via vacc aliased on kvs ----
  float* vacc = (float*)&kvs[0][0];  // 8 x 512 f32 = 16 KB
#pragma unroll
  for (int j = 0; j < 8; ++j) vacc[w * DIM + lane * 8 + j] = a8[j];
  __syncthreads();
  {
    float s = 0.f;
#pragma unroll
    for (int ww = 0; ww < 8; ++ww) s += vacc[ww * DIM + t];
    outb[(long)i * DIM + t] = (bf16_t)(s * invs_s[t >> 6]);
  }
}

// ---------------- LayerNorm(a+b) ----------------
__global__ __launch_bounds__(64) void ln_k(const float* __restrict__ a,
                                           const float* __restrict__ b,
                                           const float* __restrict__ g,
                                           const float* __restrict__ beta,
                                           float* __restrict__ of,
                                           bf16_t* __restrict__ ob) {
  const int row = blockIdx.x;
  const int l = threadIdx.x;
  const float* pa = a + (long)row * DIM;
  const float* pb = b + (long)row * DIM;
  float v[8];
  float s = 0.f;
#pragma unroll
  for (int j = 0; j < 8; ++j) {
    int d = l + j * 64;
    v[j] = pa[d] + pb[d];
    s += v[j];
  }
#pragma unroll
  for (int o = 32; o > 0; o >>= 1) s += __shfl_xor(s, o);
  float mu = s * (1.f / 512.f);
  float q = 0.f;
#pragma unroll
  for (int j = 0; j < 8; ++j) {
    float dd = v[j] - mu;
    q += dd * dd;
  }
#pragma unroll
  for (int o = 32; o > 0; o >>= 1) q += __shfl_xor(q, o);
  float inv = rsqrtf(q * (1.f / 512.f) + 1e-5f);
#pragma unroll
  for (int j = 0; j < 8; ++j) {
    int d = l + j * 64;
    float y = (v[j] - mu) * inv * g[d] + beta[d];
    of[(long)row * DIM + d] = y;
    if (ob) ob[(long)row * DIM + d] = (bf16_t)y;
  }
}

// ---------------- launch ----------------
extern "C" void kernel_launch(void* const* d_in, const int* in_sizes, int n_in,
                              void* d_out, int out_size, void* d_ws, size_t ws_size,
                              hipStream_t stream) {
  const float* x = (const float*)d_in[0];
  const int* ei = (const int*)d_in[1];
  const float* ew = (const float*)d_in[2];
  const float* Wqkv = (const float*)d_in[3];
  const float* bqkv = (const float*)d_in[4];
  const float* Wo = (const float*)d_in[5];
  const float* bo = (const float*)d_in[6];
  const float* W1 = (const float*)d_in[7];
  const float* b1 = (const float*)d_in[8];
  const float* g1 = (const float*)d_in[9];
  const float* be1 = (const float*)d_in[10];
  const float* g2 = (const float*)d_in[11];
  const float* be2 = (const float*)d_in[12];
  float* out = (float*)d_out;
  const int E = in_sizes[1] / 2;

  char* ws = (char*)d_ws;
  bf16_t* qkvb = (bf16_t*)(ws + 0);           // 12,582,912 B
  bf16_t* xb = (bf16_t*)(ws + 12582912);      // 4,194,304
  bf16_t* Wqkvb = (bf16_t*)(ws + 16777216);   // 1,572,864
  bf16_t* Wob = (bf16_t*)(ws + 18350080);     // 524,288
  bf16_t* W1b = (bf16_t*)(ws + 18874368);     // 524,288
  bf16_t* outb = (bf16_t*)(ws + 19398656);    // 4,194,304
  float* h = (float*)(ws + 23592960);         // 8,388,608
  bf16_t* hb = (bf16_t*)(ws + 31981568);      // 4,194,304
  float* f = (float*)(ws + 36175872);         // 8,388,608 (end 44,564,480)
  // CSR buffers alias the h region (h is written only after attention is done)
  uint* deg = (uint*)(ws + 23592960);         // 16,384
  int* colv = (int*)(ws + 23609344);          // 1,572,864
  uint* eidv = (uint*)(ws + 25182208);        // 1,572,864 (end 26,755,072 < h end)
  float* attn_out = (float*)(ws + 0);         // alias over dead qkvb

  cast_all_k<<<3328, 256, 0, stream>>>(x, Wqkv, Wo, W1, xb, Wqkvb, Wob, W1b, deg);
  fill_bucket_k<<<(E + 255) / 256, 256, 0, stream>>>(ei, deg, colv, eidv, E);

  // QKV projection (bf16 out): 12 x 32 = 384 blocks, 128x128 tile
  gemm128_bt<<<dim3(QKVD / 128, NNODES / 128), 256, 0, stream>>>(
      xb, Wqkvb, bqkv, qkvb, NNODES, QKVD, DIM);

  // fused sparse attention (8 waves per row, LDS bulk staging)
  attn_stage_k<<<NNODES, 512, 0, stream>>>(qkvb, ew, deg, colv, eidv, outb);

  // output projection (f32 out, aliases qkvb space): 8 x 32 = 256 blocks
  gemm_bt<false><<<dim3(DIM / 64, NNODES / 128), 256, 0, stream>>>(
      outb, Wob, bo, (void*)attn_out, NNODES, DIM, DIM);

  // LN1: h = LN(x + attn_out), also bf16 copy for FFN GEMM
  ln_k<<<NNODES, 64, 0, stream>>>(x, attn_out, g1, be1, h, hb);

  // FFN: f = hb @ W1^T + b1
  gemm_bt<false><<<dim3(DIM / 64, NNODES / 128), 256, 0, stream>>>(
      hb, W1b, b1, (void*)f, NNODES, DIM, DIM);

  // LN2 -> out
  ln_k<<<NNODES, 64, 0, stream>>>(h, f, g2, be2, out, nullptr);
}